// Round 8
// baseline (748.878 us; speedup 1.0000x reference)
//
#include <hip/hip_runtime.h>
#include <cstddef>
#include <cstdint>

#define PI_F 3.14159265358979323846f

typedef __attribute__((ext_vector_type(8))) short short8;   // 8 bf16 = 4 VGPRs
typedef __attribute__((ext_vector_type(4))) float floatx4;  // MFMA acc

template<int V> struct IC { static constexpr int value = V; };

__device__ __forceinline__ short f2bf(float f) {
    union { float f; unsigned u; } v; v.f = f;
    unsigned r = v.u + 0x7FFFu + ((v.u >> 16) & 1u);   // RNE
    return (short)(r >> 16);
}

// ---------------------------------------------------------------------------
// Weight transpose+convert: Abf[m][k'] = bf16(A[m][c*K2 + tap]), k' = tap*Cp+c
// Zero-pads m in [M,Mpad), c in [C,Cp), tap in [K2, Kp/Cp).
// ---------------------------------------------------------------------------
__global__ __launch_bounds__(256) void wtrans_kernel(
    const float* __restrict__ A, short* __restrict__ Abf,
    int M, int Mpad, int K2, int C, int Cp, int Kp, int Korig)
{
    int idx = blockIdx.x * 256 + threadIdx.x;
    if (idx >= Mpad * Kp) return;
    int m = idx / Kp;
    int k = idx - m * Kp;
    int tap = (unsigned)k / (unsigned)Cp;
    int c   = k - tap * Cp;
    float v = 0.f;
    if (m < M && tap < K2 && c < C) v = A[(size_t)m * Korig + c * K2 + tap];
    Abf[idx] = f2bf(v);
}

__global__ __launch_bounds__(256) void zero_kernel(float* __restrict__ p, int n)
{
    int i = blockIdx.x * 256 + threadIdx.x;
    if (i < n) p[i] = 0.f;
}

// Fused zero of the three non-aliased SK outputs (x2, x31, d_out) — hoisted
// to the start of the call (nothing touches them before their conv).
__global__ __launch_bounds__(256) void zero3_kernel(
    float* __restrict__ a, int na, float* __restrict__ b, int nb,
    float* __restrict__ c, int nc)
{
    int i = blockIdx.x * 256 + threadIdx.x;
    if (i < na) { a[i] = 0.f; return; }
    i -= na;
    if (i < nb) { b[i] = 0.f; return; }
    i -= nb;
    if (i < nc) c[i] = 0.f;
}

// ---------------------------------------------------------------------------
// Fused spherical-conv GEMM, bf16 MFMA, channel-innermost K.
// ROUND-25: REVERT r24 (segment-state hoisting regressed 684->715: VALU
// dropped 43.6->31.8% but stall grew more; unexplained -> abandoned) back to
// the r23 base, plus L6 WINDOWED STAGING (WIN template param): L6 is the
// only layer whose block covers HALF the row (Wo=128, 64 outputs) yet
// stageTile fetched FULL rows -> 2x overstage. With nHo=1 the needed cols
// are one contiguous span/tap: stage an 80-col (src2) / 48-col (src1)
// wrapped window -> staged bytes/tap 192->139KB, stage instrs 8->5 / 4->3,
// row LDS 32->20KB (occupancy +1 block/CU). Window/unit split via magic-mul
// div (exact over index range); interp indexes the window linearly.
// r23: direct-path (L1,L2) register software pipeline. r22: CS=6 for L1.
// r21: constexpr-stride ds_read2 interp. r20: single-buffered Bs in COOP.
// r19: cooperative row staging. XCD swizzle, split-K atomics, BN partials.
// ---------------------------------------------------------------------------
#define BNT 64
#define BKT 32
#define LDK 40

template<int MW, int SK, int LGW, int UP, int LGWO, int CS, int WIN>
__global__ __launch_bounds__(256) void sconv_mfma_kernel(
    const short* __restrict__ Abf,
    const float* __restrict__ src1, const float* __restrict__ src2,
    float2* __restrict__ part, int nBlkN,
    int C1, int Ctot, int Cp, int H, int W, int up1,
    int K2, int ksz, int stride, int lWo, int lHo, float delta,
    float* __restrict__ Y, int M, int Kp, int N, int lgM)
{
    __shared__ short Bs[(LGW != 0) ? 1 : 2][BNT][LDK];  // COOP: 2 bar/tile -> 1 buf
    __shared__ float4 tab[64];          // max nHo*K2 = 49 over all layers
    extern __shared__ __align__(16) char dynLds[];   // COOP row buffer

    constexpr int LGSK = (SK == 1) ? 0 : ((SK == 2) ? 1 : 2);

    const int tid = threadIdx.x;
    // ---- XCD swizzle (total % 8 == 0 for all layers) ----
    const int total = gridDim.x;
    const int pid = blockIdx.x;
    const int logical = (pid & 7) * (total >> 3) + (pid >> 3);
    const int mblk = logical & ((1 << lgM) - 1);
    const int rest = logical >> lgM;
    const int kslice = rest & (SK - 1);
    const int nblk = rest >> LGSK;
    const int m0 = mblk * (MW * 64);
    const int n0 = nblk * BNT;

    const int Wo  = 1 << lWo;
    const int Ho  = 1 << lHo;
    const int HW  = 1 << (lWo + lHo);

    // ---- per-block grid table: (hoLocal, tap) -> {fr, dcol, r0i, r1i} ----
    const int nHo  = (lWo >= 6) ? 1 : (BNT >> lWo);
    const int nEnt = nHo * K2;
    const int hoBase = (n0 >> lWo) & (Ho - 1);
    if (tid < nEnt) {
        int hoL = tid / K2;
        int i   = tid - hoL * K2;
        int ho_g = hoBase + hoL;
        int jy = i / ksz, jx = i - jy * ksz;
        float halfk = (ksz - 1) * 0.5f;
        float yy = tanf(delta / (float)ksz * ((float)jy - halfk));
        float xx = tanf(delta / (float)ksz * ((float)jx - halfk));
        float rho = sqrtf(xx * xx + yy * yy);
        float rho_s = (rho == 0.f) ? 1.f : rho;
        float nu = atanf(rho);
        float lat0 = PI_F * 0.5f - ((float)(ho_g * stride) + 0.5f) * (PI_F / (float)H);
        float sl = sinf(lat0), cl = cosf(lat0);
        float sn = sinf(nu),  cn = cosf(nu);
        float arg = cn * sl + (yy / rho_s) * sn * cl;
        arg = fminf(1.f, fmaxf(-1.f, arg));
        float lat = asinf(arg);
        float dlon = atan2f(xx * sn, rho * cl * cn - yy * sl * sn);
        float row = (PI_F * 0.5f - lat) / PI_F * (float)H - 0.5f;
        float dcol = dlon / (2.f * PI_F) * (float)W;
        float r0f = floorf(row);
        float fr = row - r0f;
        int r0 = (int)r0f;
        int r0i = min(max(r0, 0), H - 1);
        int r1i = min(max(r0 + 1, 0), H - 1);
        tab[tid] = make_float4(fr, dcol, __int_as_float(r0i), __int_as_float(r1i));
    }

    // ---- B staging geometry (lane nn = coalesced wo) ----
    const int nn    = tid & 63;
    const int kslot = tid >> 6;         // wave-uniform
    const int n_s  = n0 + nn;
    const int wo_s = n_s & (Wo - 1);
    const int hoL_s = nn >> lWo;
    const int b_s  = n_s >> (lWo + lHo);   // block-uniform (HW multiple of 64)
    const int tabBase = hoL_s * K2;
    const float wo_px = (float)(wo_s * stride);
    const int n0w = (n0 & (Wo - 1)) * stride;   // block's first output col px
    const int Hs = H >> up1, Ws = W >> up1;
    const int plane1 = Hs * Ws;
    const int plane2 = H * W;
    // block-uniform bases -> force into SGPRs so tile setup stays scalar
    const unsigned boff1 = (unsigned)__builtin_amdgcn_readfirstlane(
        (int)(b_s * C1 * plane1));
    const unsigned boff2 = (unsigned)__builtin_amdgcn_readfirstlane(
        (int)(b_s * (Ctot - C1) * plane2));

    // ---- K-slice bounds + (tap, cb) init at slice start ----
    const int Tper = (Kp / BKT) / SK;
    const int t0 = kslice * Tper;
    const bool smallC = (Cp < 32);      // layer 1 only (Cp=8, never split)
    int tap, cb;
    if (smallC) { tap = kslot; cb = 0; }
    else {
        int prog = t0 * BKT;            // Cp % 32 == 0 for all split layers
        tap = prog / Cp;
        cb  = prog - tap * Cp + kslot * 8;
    }
    const int dtap = smallC ? (32 / Cp) : 0;

    // ---- wave/lane decomposition: wave tile = MW*16 rows x 64 cols ----
    const int wave = tid >> 6;
    const int wrow = wave * (MW * 16);
    const int lane = tid & 63;
    const int l16  = lane & 15;
    const int quad = lane >> 4;

    const short* pA[MW];
#pragma unroll
    for (int i = 0; i < MW; i++)
        pA[i] = Abf + (size_t)(m0 + wrow + i * 16 + l16) * Kp + quad * 8;

    floatx4 acc[MW][4];
#pragma unroll
    for (int i = 0; i < MW; i++)
#pragma unroll
        for (int j = 0; j < 4; j++)
            acc[i][j] = (floatx4){0.f, 0.f, 0.f, 0.f};

    if constexpr (LGW == 0) {
        // ======== direct-gather path (L1, L2), software-pipelined =========
        constexpr int CSX = (CS > 0) ? CS : 8;
        struct QS {
            float q00[CSX], q01[CSX], q10[CSX], q11[CSX];
            float w00, w01, w10, w11;
        };
        QS qa, qb;

        // issue the gathers for the CURRENT (tap, cb) state into q; advance.
        auto issueQ = [&](QS& q) {
            const int tapS = __builtin_amdgcn_readfirstlane(tap);
            const int cbS  = __builtin_amdgcn_readfirstlane(cb);
            const int tapc = min(tapS, K2 - 1);      // clamp for K-pad
            const float4 e = tab[tabBase + tapc];
            const float fr = e.x;
            const float col = wo_px + e.y;
            const int r0i = __float_as_int(e.z);
            const int r1i = __float_as_int(e.w);
            const float cf = floorf(col);
            const float fc = col - cf;
            const int c0 = ((int)cf) & (W - 1);
            const int c1 = (c0 + 1) & (W - 1);
            const float w11 = fr * fc;
            q.w11 = w11;
            q.w10 = fr - w11;             // fr*(1-fc)
            q.w01 = fc - w11;             // (1-fr)*fc
            q.w00 = 1.f - fr - fc + w11;  // (1-fr)*(1-fc)

            const char* sbase; unsigned o00, o01, o10, o11, planeB;
            if (cbS < C1) {              // SCALAR branch (cbS in SGPR)
                const int ra = (r0i >> up1) * Ws, rb = (r1i >> up1) * Ws;
                const int ca = c0 >> up1, cx = c1 >> up1;
                const unsigned base = boff1 + (unsigned)cbS * (unsigned)plane1;
                o00 = (base + ra + ca) * 4u; o01 = (base + ra + cx) * 4u;
                o10 = (base + rb + ca) * 4u; o11 = (base + rb + cx) * 4u;
                planeB = (unsigned)plane1 * 4u; sbase = (const char*)src1;
            } else {
                const int ra = r0i * W, rb = r1i * W;
                const unsigned base = boff2 + (unsigned)(cbS - C1) * (unsigned)plane2;
                o00 = (base + ra + c0) * 4u; o01 = (base + ra + c1) * 4u;
                o10 = (base + rb + c0) * 4u; o11 = (base + rb + c1) * 4u;
                planeB = (unsigned)plane2 * 4u; sbase = (const char*)src2;
            }
#pragma unroll
            for (int j = 0; j < CSX; j++) {
                q.q00[j] = *(const float*)(sbase + o00);
                q.q01[j] = *(const float*)(sbase + o01);
                q.q10[j] = *(const float*)(sbase + o10);
                q.q11[j] = *(const float*)(sbase + o11);
                o00 += planeB; o01 += planeB; o10 += planeB; o11 += planeB;
            }
            // advance (tap, cb)
            if (smallC) { tap += dtap; }
            else { cb += 32; if (cb >= Cp) { cb -= Cp; tap++; } }
        };

        auto interpStoreD = [&](const QS& q, int buf) {
            unsigned pk[4];
#pragma unroll
            for (int jj = 0; jj < 4; jj++) {
                if (2 * jj < CSX) {
                    float v0 = q.w00 * q.q00[2 * jj] + q.w01 * q.q01[2 * jj]
                             + q.w10 * q.q10[2 * jj] + q.w11 * q.q11[2 * jj];
                    float v1 = 0.f;
                    if (2 * jj + 1 < CSX)
                        v1 = q.w00 * q.q00[2 * jj + 1] + q.w01 * q.q01[2 * jj + 1]
                           + q.w10 * q.q10[2 * jj + 1] + q.w11 * q.q11[2 * jj + 1];
                    unsigned rr;
                    asm("v_cvt_pk_bf16_f32 %0, %1, %2"
                        : "=v"(rr) : "v"(v0), "v"(v1));
                    pk[jj] = rr;
                } else {
                    pk[jj] = 0u;         // zero-padded channels (finite!)
                }
            }
            *(uint4*)&Bs[buf][nn][kslot * 8] =
                make_uint4(pk[0], pk[1], pk[2], pk[3]);
        };

        auto mfmaStep = [&](int t) {
            const int k0 = t * BKT;
            const int buf = t & 1;
            short8 af[MW];
#pragma unroll
            for (int i = 0; i < MW; i++)
                af[i] = *(const short8*)(pA[i] + k0);
            short8 bfv[4];
#pragma unroll
            for (int j = 0; j < 4; j++)
                bfv[j] = *(const short8*)&Bs[buf][j * 16 + l16][quad * 8];
#pragma unroll
            for (int i = 0; i < MW; i++)
#pragma unroll
                for (int j = 0; j < 4; j++)
                    acc[i][j] = __builtin_amdgcn_mfma_f32_16x16x32_bf16(
                        af[i], bfv[j], acc[i][j], 0, 0, 0);
        };

        __syncthreads();   // table ready

        issueQ(qa);        // tile t0
        int t = t0;
        for (; t + 2 <= t0 + Tper; t += 2) {
            issueQ(qb);                 // tile t+1 in flight
            interpStoreD(qa, t & 1);    // consume tile t
            __syncthreads();
            mfmaStep(t);
            issueQ(qa);                 // tile t+2 in flight (harmless if OOB:
                                        // tapc clamps, cb wraps -> valid addrs)
            interpStoreD(qb, (t + 1) & 1);
            __syncthreads();
            mfmaStep(t + 1);
        }
        if (t < t0 + Tper) {            // odd Tper tail (13 for L1/L2)
            interpStoreD(qa, t & 1);
            __syncthreads();
            mfmaStep(t);
        }
    } else {
        // =================== COOP row-staged path (L3..L6) ================
        constexpr int WC    = 1 << LGW;
        constexpr int LGWS1 = LGW - UP;        // src1 row width (log2 floats)
        constexpr int NHO   = (LGWO >= 6) ? 1 : (64 >> LGWO);
        constexpr int NHO2  = NHO * 2;
        constexpr int LG2NHO = (NHO == 4) ? 3 : ((NHO == 2) ? 2 : 1);
        constexpr int NU    = 64 * NHO;        // units = 32ch x 2rows x NHO
        constexpr bool WND  = (WIN > 0);       // windowed staging (L6, NHO==1)
        constexpr int WIN1  = 48;              // src1 window cols (WIN==80)
        const int kslotU = __builtin_amdgcn_readfirstlane(kslot);

        // rows layout (full-row mode): unit u (= chL*2NHO + rowSel*NHO + hoL)
        // occupies Wsrc floats at dynLds + u*Wsrc*4; windowed mode: WIN cols.
        // Staged by global_load_lds_dwordx4, 1024B/instr (linear dest).
        auto stageTile = [&](int tapT, int cbT) {
            const bool s1 = (cbT < C1);
            const float* srcT = s1 ? src1 : src2;
            const int lgWt = s1 ? LGWS1 : LGW;
            const int upT  = s1 ? UP : 0;
            const int plT  = s1 ? plane1 : plane2;
            const unsigned chB = s1
                ? (boff1 + (unsigned)cbT * (unsigned)plane1)
                : (boff2 + (unsigned)(cbT - C1) * (unsigned)plane2);
            const int tapc2 = min(tapT, K2 - 1);
            const int lgLPU = lgWt - 2;                 // lanes per unit
            const int NIw = (NU << lgWt) >> 10;         // instrs per wave
            const int uW  = lane >> lgLPU;
            const unsigned colB = (unsigned)(lane & ((1 << lgLPU) - 1)) << 2;
            for (int ii = 0; ii < NIw; ii++) {
                const int idx = kslotU * NIw + ii;
                const int u = (idx << (6 - lgLPU)) + uW;
                const int chL = u >> LG2NHO;
                const int rem = u & (NHO2 - 1);
                const int hoL = rem & (NHO - 1);
                const float4 e = tab[hoL * K2 + tapc2];
                const float rsel = (rem >> (LG2NHO - 1)) ? e.w : e.z;
                const int r = __float_as_int(rsel) >> upT;
                const float* gp = srcT + (chB + (unsigned)chL * (unsigned)plT
                                          + ((unsigned)r << lgWt) + colB);
                __builtin_amdgcn_global_load_lds(
                    (const __attribute__((address_space(1))) void*)gp,
                    (__attribute__((address_space(3))) void*)(dynLds + (size_t)idx * 1024),
                    16, 0, 0);
            }
        };

        // windowed stage (NHO==1 only): WIN cols src2 / WIN1 cols src1.
        auto stageTileWnd = [&](int tapT, int cbT) {
            const bool s1 = (cbT < C1);
            const float* srcT = s1 ? src1 : src2;
            const int lgWt = s1 ? LGWS1 : LGW;
            const int upT  = s1 ? UP : 0;
            const int plT  = s1 ? plane1 : plane2;
            const unsigned chB = s1
                ? (boff1 + (unsigned)cbT * (unsigned)plane1)
                : (boff2 + (unsigned)(cbT - C1) * (unsigned)plane2);
            const int tapc2 = min(tapT, K2 - 1);
            const float4 e = tab[tapc2];                // NHO==1 -> hoL=0
            const int NIw = s1 ? (NU * WIN1 * 4 / 4096) : (NU * WIN * 4 / 4096);
            const int W16 = s1 ? (WIN1 / 4) : (WIN / 4);   // 12 : 20
            const unsigned MG = s1 ? 5462u : 3277u;     // ceil(65536/W16)
            const int cst  = (n0w + (int)floorf(e.y) - 3) & ~7;
            const int cstB = (cst >> upT) * 4;          // window start, bytes
            const int rmB  = (4 << lgWt) - 1;           // source row bytes - 1
            const int r0 = __float_as_int(e.z) >> upT;
            const int r1 = __float_as_int(e.w) >> upT;
            for (int ii = 0; ii < NIw; ii++) {
                const int idx = kslotU * NIw + ii;
                const unsigned c16 = (unsigned)(idx << 6) + (unsigned)lane;
                const unsigned u = (c16 * MG) >> 16;    // unit = c16 / W16
                const int remB = (int)((c16 - u * (unsigned)W16) << 4);
                const int chL = (int)(u >> 1);
                const int r = (u & 1) ? r1 : r0;
                const int gcol = (cstB + remB) & rmB;   // wrapped, 16B-aligned
                const float* rowp = srcT + (chB + (unsigned)chL * (unsigned)plT
                                            + ((unsigned)r << lgWt));
                __builtin_amdgcn_global_load_lds(
                    (const __attribute__((address_space(1))) void*)
                        ((const char*)rowp + gcol),
                    (__attribute__((address_space(3))) void*)(dynLds + (size_t)idx * 1024),
                    16, 0, 0);
            }
        };

        int tapS, cb0S;
        {
            int prog = t0 * BKT;
            tapS = prog / Cp;
            cb0S = prog - tapS * Cp;
        }

        __syncthreads();   // table ready

        if constexpr (WND) stageTileWnd(tapS, cb0S);
        else               stageTile(tapS, cb0S);
        short8 afc[MW];
#pragma unroll
        for (int i2 = 0; i2 < MW; i2++)
            afc[i2] = *(const short8*)(pA[i2] + t0 * BKT);

        for (int t = t0; t < t0 + Tper; t++) {
            tapS = __builtin_amdgcn_readfirstlane(tapS);
            cb0S = __builtin_amdgcn_readfirstlane(cb0S);
            const bool isS1 = (cb0S < C1);
            const int tapcI  = min(tapS, K2 - 1);

            asm volatile("s_waitcnt vmcnt(0)" ::: "memory");
            __syncthreads();             // bar1: rows(t) + afc landed

            // ---- interpolate from LDS rows -> Bs[0] ----
            // constexpr strides -> ds_read2_b32 {row0,row1} per corner pair
            auto interpStore = [&](auto lgwc, auto upc) {
                constexpr int LGWSRC = decltype(lgwc)::value;
                constexpr int UPX    = decltype(upc)::value;
                constexpr int STEPR  = NHO << LGWSRC;   // dwords, <=128
                constexpr int STEPC  = NHO2 << LGWSRC;
                const float4 e2 = tab[tabBase + tapcI];
                const float fr = e2.x;
                const float col = wo_px + e2.y;
                const float cf = floorf(col);
                const float fc = col - cf;
                const int c0 = ((int)cf) & (WC - 1);
                const int c1 = (c0 + 1) & (WC - 1);
                const int c0s = c0 >> UPX, c1s = c1 >> UPX;
                const float w11 = fr * fc;
                const float w10 = fr - w11;             // fr*(1-fc)
                const float w01 = fc - w11;             // (1-fr)*fc
                const float w00 = 1.f - fr - fc + w11;  // (1-fr)*(1-fc)
                const float* rowsF = (const float*)dynLds;
                const float* pc0 = rowsF
                    + ((((kslot * 8) << LG2NHO) + hoL_s) << LGWSRC) + c0s;
                const float* pc1 = pc0 + (c1s - c0s);
                float vv[8];
#pragma unroll
                for (int j = 0; j < 8; j++) {
                    const float x00 = pc0[0];
                    const float x10 = pc0[STEPR];
                    const float x01 = pc1[0];
                    const float x11 = pc1[STEPR];
                    vv[j] = w00 * x00 + w01 * x01 + w10 * x10 + w11 * x11;
                    pc0 += STEPC; pc1 += STEPC;
                }
                unsigned pk[4];
#pragma unroll
                for (int jj = 0; jj < 4; jj++) {
                    unsigned rr;
                    asm("v_cvt_pk_bf16_f32 %0, %1, %2"
                        : "=v"(rr) : "v"(vv[2 * jj]), "v"(vv[2 * jj + 1]));
                    pk[jj] = rr;
                }
                *(uint4*)&Bs[0][nn][kslot * 8] =
                    make_uint4(pk[0], pk[1], pk[2], pk[3]);
            };
            // windowed variant: window-linear col index, NHO==1
            auto interpStoreW = [&](auto upc, auto winc) {
                constexpr int UPX = decltype(upc)::value;
                constexpr int WW  = decltype(winc)::value;
                constexpr int STEPR = WW;               // row1 offset (NHO=1)
                constexpr int STEPC = 2 * WW;           // next channel
                const float4 e2 = tab[tapcI];           // tabBase==0
                const float fr = e2.x;
                const float col = wo_px + e2.y;
                const float cf = floorf(col);
                const float fc = col - cf;
                const int c0u = (int)cf;                // unwrapped
                const int cst = (n0w + (int)floorf(e2.y) - 3) & ~7;
                const int wc0 = (c0u >> UPX) - (cst >> UPX);
                const int wc1 = ((c0u + 1) >> UPX) - (cst >> UPX);
                const float w11 = fr * fc;
                const float w10 = fr - w11;
                const float w01 = fc - w11;
                const float w00 = 1.f - fr - fc + w11;
                const float* rowsF = (const float*)dynLds;
                const float* pc0 = rowsF + (kslot * 16) * WW + wc0;
                const float* pc1 = pc0 + (wc1 - wc0);
                float vv[8];
#pragma unroll
                for (int j = 0; j < 8; j++) {
                    const float x00 = pc0[0];
                    const float x10 = pc0[STEPR];
                    const float x01 = pc1[0];
                    const float x11 = pc1[STEPR];
                    vv[j] = w00 * x00 + w01 * x01 + w10 * x10 + w11 * x11;
                    pc0 += STEPC; pc1 += STEPC;
                }
                unsigned pk[4];
#pragma unroll
                for (int jj = 0; jj < 4; jj++) {
                    unsigned rr;
                    asm("v_cvt_pk_bf16_f32 %0, %1, %2"
                        : "=v"(rr) : "v"(vv[2 * jj]), "v"(vv[2 * jj + 1]));
                    pk[jj] = rr;
                }
                *(uint4*)&Bs[0][nn][kslot * 8] =
                    make_uint4(pk[0], pk[1], pk[2], pk[3]);
            };
            if constexpr (WND) {
                if (isS1) interpStoreW(IC<UP>{}, IC<WIN1>{});
                else      interpStoreW(IC<0>{},  IC<WIN>{});
            } else {
                if (isS1) interpStore(IC<LGWS1>{}, IC<UP>{});
                else      interpStore(IC<LGW>{},   IC<0>{});
            }

            __syncthreads();             // bar2: Bs ready; rows reusable

            // ---- issue next tile's A-frags + rows BEFORE the MFMA ----
            int tapN = tapS, cbN = cb0S + BKT;
            if (cbN >= Cp) { cbN = 0; tapN = tapS + 1; }
            const bool more = (t + 1 < t0 + Tper);
            short8 afn[MW];
            if (more) {
#pragma unroll
                for (int i2 = 0; i2 < MW; i2++)
                    afn[i2] = *(const short8*)(pA[i2] + (t + 1) * BKT);
                if constexpr (WND) stageTileWnd(tapN, cbN);
                else               stageTile(tapN, cbN);
            }

            short8 bfr[4];
#pragma unroll
            for (int j = 0; j < 4; j++)
                bfr[j] = *(const short8*)&Bs[0][j * 16 + l16][quad * 8];
#pragma unroll
            for (int i2 = 0; i2 < MW; i2++)
#pragma unroll
                for (int j = 0; j < 4; j++)
                    acc[i2][j] = __builtin_amdgcn_mfma_f32_16x16x32_bf16(
                        afc[i2], bfr[j], acc[i2][j], 0, 0, 0);

            tapS = tapN; cb0S = cbN;
            if (more) {
#pragma unroll
                for (int i2 = 0; i2 < MW; i2++) afc[i2] = afn[i2];
            }
        }
    }

    // ---- epilogue (C/D layout col=lane&15, row=quad*4+reg) ----
    if (SK == 1) {
        // plain store + BN partials to UNIQUE per-(m,nblk) slots (no atomics)
#pragma unroll
        for (int i = 0; i < MW; i++) {
#pragma unroll
            for (int rr = 0; rr < 4; rr++) {
                const int m = m0 + wrow + i * 16 + quad * 4 + rr;
                const bool mv = (m < M);
                float s = 0.f, q = 0.f;
#pragma unroll
                for (int j = 0; j < 4; j++) {
                    const int n = n0 + j * 16 + l16;
                    const float v = acc[i][j][rr];
                    s += v; q += v * v;
                    if (mv) {
                        const int wo = n & (Wo - 1);
                        const int r  = n >> lWo;
                        const int ho = r & (Ho - 1);
                        const int b_ = r >> lHo;
                        Y[((size_t)b_ * M + m) * HW + (ho << lWo) + wo] = v;
                    }
                }
#pragma unroll
                for (int mask = 1; mask < 16; mask <<= 1) {
                    s += __shfl_xor(s, mask);
                    q += __shfl_xor(q, mask);
                }
                if (mv && l16 == 0)
                    part[(size_t)m * nBlkN + nblk] = make_float2(s, q);
            }
        }
    } else {
        // split-K: accumulate into zero-initialized Y (native f32 atomic add)
#pragma unroll
        for (int i = 0; i < MW; i++) {
#pragma unroll
            for (int j = 0; j < 4; j++) {
                const int n = n0 + j * 16 + l16;
                const int wo = n & (Wo - 1);
                const int r  = n >> lWo;
                const int ho = r & (Ho - 1);
                const int b_ = r >> lHo;
#pragma unroll
                for (int rr = 0; rr < 4; rr++) {
                    const int m = m0 + wrow + i * 16 + quad * 4 + rr;
                    if (m < M)
                        unsafeAtomicAdd(
                            &Y[((size_t)b_ * M + m) * HW + (ho << lWo) + wo],
                            acc[i][j][rr]);
                }
            }
        }
    }
}

// ---------------------------------------------------------------------------
// BN stats for split-K layers: grid (Co, 8), float partials -> part[c*8+sp].
// ---------------------------------------------------------------------------
__global__ __launch_bounds__(256) void bn_stats8_kernel(
    const float* __restrict__ Y, float2* __restrict__ part,
    int Co, int HW, int B)
{
    int co = blockIdx.x;
    int sp = blockIdx.y;
    int tid = threadIdx.x;
    int Nt = B * HW;
    int len = Nt >> 3;                  // Nt multiple of 8 (HW >= 512)
    int start = sp * len, end = start + len;
    float s = 0.f, q = 0.f;
    for (int idx = start + tid; idx < end; idx += 256) {
        int b = idx / HW; int o = idx - b * HW;
        float v = Y[((size_t)b * Co + co) * HW + o];
        s += v; q += v * v;
    }
    __shared__ float sh_s[256], sh_q[256];
    sh_s[tid] = s; sh_q[tid] = q;
    __syncthreads();
    for (int off = 128; off > 0; off >>= 1) {
        if (tid < off) { sh_s[tid] += sh_s[tid + off]; sh_q[tid] += sh_q[tid + off]; }
        __syncthreads();
    }
    if (tid == 0)
        part[co * 8 + sp] = make_float2(sh_s[0], sh_q[0]);
}

// ---------------------------------------------------------------------------
// BN finalize (L1 only, slots=nBlkN): reduce -> {sc, sf}.
// ---------------------------------------------------------------------------
__global__ __launch_bounds__(256) void bn_finalize_kernel(
    const float2* __restrict__ part, float2* __restrict__ scSf,
    const float* __restrict__ g, const float* __restrict__ bb,
    int nBlkN, int Nt)
{
    int c = blockIdx.x;
    int tid = threadIdx.x;
    double s = 0.0, q = 0.0;
    for (int k = tid; k < nBlkN; k += 256) {
        float2 p = part[(size_t)c * nBlkN + k];
        s += p.x; q += p.y;
    }
    __shared__ double sh_s[256], sh_q[256];
    sh_s[tid] = s; sh_q[tid] = q;
    __syncthreads();
    for (int off = 128; off > 0; off >>= 1) {
        if (tid < off) { sh_s[tid] += sh_s[tid + off]; sh_q[tid] += sh_q[tid + off]; }
        __syncthreads();
    }
    if (tid == 0) {
        double mean = sh_s[0] / Nt;
        double var = sh_q[0] / Nt - mean * mean;
        if (var < 0.0) var = 0.0;
        float sc = g[c] / sqrtf((float)var + 1e-5f);
        scSf[c] = make_float2(sc, bb[c] - (float)mean * sc);
    }
}

// Normalize + ReLU reading finalized {sc, sf} (L1 path).
__global__ __launch_bounds__(256) void bn_apply_kernel(
    float* __restrict__ Y, const float2* __restrict__ scSf,
    int Co, int HW, int total)
{
    int idx = blockIdx.x * 256 + threadIdx.x;
    if (idx >= total) return;
    int c = (idx / HW) % Co;
    float2 s = scSf[c];
    float v = Y[idx] * s.x + s.y;
    Y[idx] = v > 0.f ? v : 0.f;
}

// SK layers: finalize folded in — per-block reduce of the 8 partial slots
// (channel uniform per block since 256 | HW for all SK layers).
__global__ __launch_bounds__(256) void bn_apply_sk_kernel(
    float* __restrict__ Y, const float2* __restrict__ part,
    const float* __restrict__ g, const float* __restrict__ bb,
    int Co, int HW, int Nt, int total)
{
    int idx = blockIdx.x * 256 + threadIdx.x;
    int c = (idx / HW) % Co;
    __shared__ float s_sc, s_sf;
    if (threadIdx.x == 0) {
        double s = 0.0, q = 0.0;
        for (int p = 0; p < 8; p++) {
            float2 pp = part[c * 8 + p];
            s += pp.x; q += pp.y;
        }
        double mean = s / Nt;
        double var = q / Nt - mean * mean;
        if (var < 0.0) var = 0.0;
        float sc = g[c] / sqrtf((float)var + 1e-5f);
        s_sc = sc;
        s_sf = bb[c] - (float)mean * sc;
    }
    __syncthreads();
    if (idx >= total) return;
    float v = Y[idx] * s_sc + s_sf;
    Y[idx] = v > 0.f ? v : 0.f;
}

// ---------------------------------------------------------------------------
// Host orchestration. Workspace ~36 MB. Scratch Q reuse by lifetime:
// x1=Q (L1-2), x3=Q (L3-4), x4=Q (L5-6), x41=Q+512K (L6-7), x5=Q+1M (L7-8).
// Zeros for non-aliased SK outputs (x2, x31, d_out) hoisted+fused upfront;
// Q-aliased outputs (x3, x4, x41, x5) zeroed inline.
// ---------------------------------------------------------------------------
extern "C" void kernel_launch(void* const* d_in, const int* in_sizes, int n_in,
                              void* d_out, int out_size, void* d_ws, size_t ws_size,
                              hipStream_t stream)
{
    const int B = 4;
    char* ws = (char*)d_ws;
    size_t off = 0;
    auto allocb = [&](size_t bytes) -> void* {
        void* p = ws + off;
        off = (off + bytes + 255) & ~(size_t)255;
        return p;
    };

    float2* part = (float2*)allocb((size_t)65536 * sizeof(float2));
    float2* scSf = (float2*)allocb(256 * sizeof(float2));
    float* x2  = (float*)allocb((size_t)B * 64  * 64 * 128 * 4);
    float* x31 = (float*)allocb((size_t)B * 128 * 32 * 64 * 4);
    float* Q   = (float*)allocb((size_t)B * 32  * 128 * 256 * 4);
    float* x1  = Q;
    float* x3  = Q;
    float* x4  = Q;
    float* x41 = Q + (size_t)B * 256 * 16 * 32;
    float* x5  = Q + 2 * (size_t)B * 256 * 16 * 32;

    //                      1     2     3    31     4    41     5     6
    static const int kH[8]  = {256, 128,  64,  32,  32,  16,  32,  64};
    static const int kW[8]  = {512, 256, 128,  64,  64,  32,  64, 128};
    static const int kK[8]  = {  7,   5,   5,   3,   3,   3,   3,   3};
    static const int kSt[8] = {  2,   2,   2,   1,   2,   1,   1,   1};
    static const int kC[8]  = {  6,  32,  64, 128, 128, 256, 384, 320};
    static const int kM[8]  = { 32,  64, 128, 128, 256, 256, 256, 128};
    // Grid tuning (r12-r16): L6 SK=2 (r16: SK=4 neutral, 2x atomic WRITE).
    static const int kMW[8] = {  1,   1,   1,   1,   1,   1,   2,   2};
    static const int kSK[8] = {  1,   2,   4,   4,   4,   4,   4,   2};

    int Cp_[8], Kp_[8], Mpad_[8];
    short* Abf[8];
    for (int i = 0; i < 8; i++) {
        int K2 = kK[i] * kK[i];
        int Cp = (kC[i] < 8) ? 8 : kC[i];
        int gran = 32 * kSK[i];
        int Kp = (K2 * Cp + gran - 1) / gran * gran;   // SK-slice aligned
        int Mpad = (kM[i] + 63) & ~63;
        Cp_[i] = Cp; Kp_[i] = Kp; Mpad_[i] = Mpad;
        Abf[i] = (short*)allocb((size_t)Mpad * Kp * sizeof(short));
    }
    (void)ws_size; (void)in_sizes; (void)n_in; (void)out_size;

    struct LCfg { const float *s1, *s2; int C1, up; float delta; int widx; float* Y; };
    const float* input = (const float*)d_in[0];
    LCfg L[8] = {
        { input, nullptr,   6, 0, PI_F / 32.f,  1, x1  },
        { x1,    nullptr,  32, 0, PI_F / 16.f,  5, x2  },
        { x2,    nullptr,  64, 0, PI_F / 4.f,   9, x3  },
        { x3,    nullptr, 128, 0, PI_F / 4.f,  13, x31 },
        { x31,   nullptr, 128, 0, PI_F / 2.f,  17, x4  },
        { x4,    nullptr, 256, 0, PI_F / 2.f,  21, x41 },
        { x41,   x31,     256, 1, PI_F / 4.f,  25, x5  },
        { x5,    x2,      256, 1, PI_F / 8.f,  29, (float*)d_out },
    };

    // hoisted fused zero of non-aliased SK outputs
    {
        int n_x2 = B * 64 * 64 * 128;
        int n_x31 = B * 128 * 32 * 64;
        int n_out = B * 128 * 64 * 128;
        int tot = n_x2 + n_x31 + n_out;
        zero3_kernel<<<dim3((tot + 255) / 256), dim3(256), 0, stream>>>(
            x2, n_x2, x31, n_x31, (float*)d_out, n_out);
    }

    for (int i = 0; i < 8; i++) {
        const LCfg& c = L[i];
        int H = kH[i], W = kW[i], k = kK[i], st = kSt[i];
        int Ho = H / st, Wo = W / st;
        int K2 = k * k;
        int C  = kC[i], M = kM[i];
        int HW = Ho * Wo;
        int N  = B * HW;
        int lWo = __builtin_ctz(Wo), lHo = __builtin_ctz(Ho);
        const float* Wt   = (const float*)d_in[c.widx];
        const float* gam  = (const float*)d_in[c.widx + 2];
        const float* bet  = (const float*)d_in[c.widx + 3];
        int total = B * M * HW;

        int tn = Mpad_[i] * Kp_[i];
        wtrans_kernel<<<dim3((tn + 255) / 256), dim3(256), 0, stream>>>(
            Wt, Abf[i], M, Mpad_[i], K2, C, Cp_[i], Kp_[i], C * K2);

        int MWi = kMW[i], SKi = kSK[i];
        int nBlkM = Mpad_[i] / (64 * MWi);
        int nBlkN = N / BNT;
        int totalBlk = nBlkN * nBlkM * SKi;        // % 8 == 0 for all layers
        int lgM = __builtin_ctz(nBlkM);

        // COOP dynamic LDS: units (64*nHo) x widest-source row (floats);
        // L6 (i==7) windowed: 64 units x 80 cols.
        size_t dynB = 0;
        if (i >= 2) {
            int nHo_i = (Wo >= 64) ? 1 : (64 / Wo);
            int w1 = W >> c.up;
            int wmax = c.s2 ? W : w1;
            if (w1 > wmax) wmax = w1;
            dynB = (size_t)(64 * nHo_i) * (size_t)wmax * 4u;
        }
        if (i == 7) dynB = (size_t)64 * 80 * 4u;   // windowed rows

        // inline zero only for Q-aliased outputs (x3, x4, x41, x5)
        if (SKi > 1 && i >= 2 && i <= 6 && c.Y != x31)
            zero_kernel<<<dim3((total + 255) / 256), dim3(256), 0, stream>>>(
                c.Y, total);

        #define CONV_ARGS Abf[i], c.s1, c.s2, part, nBlkN, \
            c.C1, C, Cp_[i], H, W, c.up, K2, k, st, lWo, lHo, c.delta, \
            c.Y, M, Kp_[i], N, lgM
        #define LAUNCH(MW_, SK_, LGW_, UP_, LGWO_, CS_, WIN_, DYN_) \
            sconv_mfma_kernel<MW_,SK_,LGW_,UP_,LGWO_,CS_,WIN_> \
                <<<dim3(totalBlk), dim3(256), DYN_, stream>>>(CONV_ARGS)
        switch (i) {
            case 0: LAUNCH(1, 1, 0, 0, 0, 6, 0, 0);     break;  // L1  direct CS=6
            case 1: LAUNCH(1, 2, 0, 0, 0, 0, 0, 0);     break;  // L2  direct
            case 2: LAUNCH(1, 4, 7, 0, 6, 0, 0, dynB);  break;  // L3  W=128 Wo=64
            case 3: LAUNCH(1, 4, 6, 0, 6, 0, 0, dynB);  break;  // L31 W=64  Wo=64
            case 4: LAUNCH(1, 4, 6, 0, 5, 0, 0, dynB);  break;  // L4  W=64  Wo=32
            case 5: LAUNCH(1, 4, 5, 0, 5, 0, 0, dynB);  break;  // L41 W=32  Wo=32
            case 6: LAUNCH(2, 4, 6, 1, 6, 0, 0, dynB);  break;  // L5  W=64  Wo=64 up
            case 7: LAUNCH(2, 2, 7, 1, 7, 0, 80, dynB); break;  // L6  windowed
        }
        #undef LAUNCH
        #undef CONV_ARGS

        if (SKi > 1) {
            bn_stats8_kernel<<<dim3(M, 8), dim3(256), 0, stream>>>(
                c.Y, part, M, HW, B);
            bn_apply_sk_kernel<<<dim3(total / 256), dim3(256), 0, stream>>>(
                c.Y, part, gam, bet, M, HW, N, total);
        } else {
            bn_finalize_kernel<<<dim3(M), dim3(256), 0, stream>>>(
                part, scSf, gam, bet, nBlkN, N);
            bn_apply_kernel<<<dim3(total / 256), dim3(256), 0, stream>>>(
                c.Y, scSf, M, HW, total);
        }
    }
}

// Round 9
// 675.674 us; speedup vs baseline: 1.1083x; 1.1083x over previous
//
#include <hip/hip_runtime.h>
#include <cstddef>
#include <cstdint>

#define PI_F 3.14159265358979323846f

typedef __attribute__((ext_vector_type(8))) short short8;   // 8 bf16 = 4 VGPRs
typedef __attribute__((ext_vector_type(4))) float floatx4;  // MFMA acc

template<int V> struct IC { static constexpr int value = V; };

__device__ __forceinline__ short f2bf(float f) {
    union { float f; unsigned u; } v; v.f = f;
    unsigned r = v.u + 0x7FFFu + ((v.u >> 16) & 1u);   // RNE
    return (short)(r >> 16);
}

// ---------------------------------------------------------------------------
// ROUND-26: ALL weight transposes batched into ONE launch (8 -> 1). Each
// element finds its layer via 8 scalar boundary compares on the concatenated
// index space. Same per-element math as the old wtrans_kernel.
// ---------------------------------------------------------------------------
struct WtArgs {
    const float* A[8];
    short* dst[8];
    int M[8], K2[8], C[8], Cp[8], Kp[8];
    int cum[9];                          // cumulative Mpad*Kp
};

__global__ __launch_bounds__(256) void wtrans_all_kernel(WtArgs a)
{
    int g = blockIdx.x * 256 + threadIdx.x;
    if (g >= a.cum[8]) return;
    int L = 0;
#pragma unroll
    for (int i = 1; i < 8; i++) L += (g >= a.cum[i]) ? 1 : 0;
    const int idx = g - a.cum[L];
    const int Kp = a.Kp[L], Cp = a.Cp[L], K2 = a.K2[L], C = a.C[L], M = a.M[L];
    int m = idx / Kp;
    int k = idx - m * Kp;
    int tap = (unsigned)k / (unsigned)Cp;
    int c   = k - tap * Cp;
    float v = 0.f;
    if (m < M && tap < K2 && c < C)
        v = a.A[L][(size_t)m * (C * K2) + c * K2 + tap];
    a.dst[L][idx] = f2bf(v);
}

__global__ __launch_bounds__(256) void zero_kernel(float* __restrict__ p, int n)
{
    int i = blockIdx.x * 256 + threadIdx.x;
    if (i < n) p[i] = 0.f;
}

// Fused zero of the three non-aliased SK outputs (x2, x31, d_out) — hoisted
// to the start of the call (nothing touches them before their conv).
__global__ __launch_bounds__(256) void zero3_kernel(
    float* __restrict__ a, int na, float* __restrict__ b, int nb,
    float* __restrict__ c, int nc)
{
    int i = blockIdx.x * 256 + threadIdx.x;
    if (i < na) { a[i] = 0.f; return; }
    i -= na;
    if (i < nb) { b[i] = 0.f; return; }
    i -= nb;
    if (i < nc) c[i] = 0.f;
}

// ---------------------------------------------------------------------------
// Fused spherical-conv GEMM, bf16 MFMA, channel-innermost K.
// ROUND-26: REVERT r24 (hoisting) and r25 (L6 window) — both regressed; L6
// is GRID-limited (1024 blocks = 4/CU) so LDS savings buy nothing there.
// Base = r23 (best, 683.8us). This round only: (a) batched wtrans (above),
// (b) L41 SK 4->8 (was 256 blocks = 1 block/CU, the only grid-starved
// layer where SK costs no extra K-pad: Kp=2304 % 256 == 0) -> 512 blocks.
// r23: direct-path (L1,L2) register software pipeline. r22: CS=6 for L1.
// r21: constexpr-stride ds_read2 interp in COOP. r20: single-buffered Bs in
// COOP. r19: cooperative row staging. XCD swizzle, split-K atomics, BN
// partials per r11-r18.
// ---------------------------------------------------------------------------
#define BNT 64
#define BKT 32
#define LDK 40

template<int MW, int SK, int LGW, int UP, int LGWO, int CS>
__global__ __launch_bounds__(256) void sconv_mfma_kernel(
    const short* __restrict__ Abf,
    const float* __restrict__ src1, const float* __restrict__ src2,
    float2* __restrict__ part, int nBlkN,
    int C1, int Ctot, int Cp, int H, int W, int up1,
    int K2, int ksz, int stride, int lWo, int lHo, float delta,
    float* __restrict__ Y, int M, int Kp, int N, int lgM)
{
    __shared__ short Bs[(LGW != 0) ? 1 : 2][BNT][LDK];  // COOP: 2 bar/tile -> 1 buf
    __shared__ float4 tab[64];          // max nHo*K2 = 49 over all layers
    extern __shared__ __align__(16) char dynLds[];   // COOP row buffer

    constexpr int LGSK = (SK == 1) ? 0 : ((SK == 2) ? 1 : ((SK == 4) ? 2 : 3));

    const int tid = threadIdx.x;
    // ---- XCD swizzle (total % 8 == 0 for all layers) ----
    const int total = gridDim.x;
    const int pid = blockIdx.x;
    const int logical = (pid & 7) * (total >> 3) + (pid >> 3);
    const int mblk = logical & ((1 << lgM) - 1);
    const int rest = logical >> lgM;
    const int kslice = rest & (SK - 1);
    const int nblk = rest >> LGSK;
    const int m0 = mblk * (MW * 64);
    const int n0 = nblk * BNT;

    const int Wo  = 1 << lWo;
    const int Ho  = 1 << lHo;
    const int HW  = 1 << (lWo + lHo);

    // ---- per-block grid table: (hoLocal, tap) -> {fr, dcol, r0i, r1i} ----
    const int nHo  = (lWo >= 6) ? 1 : (BNT >> lWo);
    const int nEnt = nHo * K2;
    const int hoBase = (n0 >> lWo) & (Ho - 1);
    if (tid < nEnt) {
        int hoL = tid / K2;
        int i   = tid - hoL * K2;
        int ho_g = hoBase + hoL;
        int jy = i / ksz, jx = i - jy * ksz;
        float halfk = (ksz - 1) * 0.5f;
        float yy = tanf(delta / (float)ksz * ((float)jy - halfk));
        float xx = tanf(delta / (float)ksz * ((float)jx - halfk));
        float rho = sqrtf(xx * xx + yy * yy);
        float rho_s = (rho == 0.f) ? 1.f : rho;
        float nu = atanf(rho);
        float lat0 = PI_F * 0.5f - ((float)(ho_g * stride) + 0.5f) * (PI_F / (float)H);
        float sl = sinf(lat0), cl = cosf(lat0);
        float sn = sinf(nu),  cn = cosf(nu);
        float arg = cn * sl + (yy / rho_s) * sn * cl;
        arg = fminf(1.f, fmaxf(-1.f, arg));
        float lat = asinf(arg);
        float dlon = atan2f(xx * sn, rho * cl * cn - yy * sl * sn);
        float row = (PI_F * 0.5f - lat) / PI_F * (float)H - 0.5f;
        float dcol = dlon / (2.f * PI_F) * (float)W;
        float r0f = floorf(row);
        float fr = row - r0f;
        int r0 = (int)r0f;
        int r0i = min(max(r0, 0), H - 1);
        int r1i = min(max(r0 + 1, 0), H - 1);
        tab[tid] = make_float4(fr, dcol, __int_as_float(r0i), __int_as_float(r1i));
    }

    // ---- B staging geometry (lane nn = coalesced wo) ----
    const int nn    = tid & 63;
    const int kslot = tid >> 6;         // wave-uniform
    const int n_s  = n0 + nn;
    const int wo_s = n_s & (Wo - 1);
    const int hoL_s = nn >> lWo;
    const int b_s  = n_s >> (lWo + lHo);   // block-uniform (HW multiple of 64)
    const int tabBase = hoL_s * K2;
    const float wo_px = (float)(wo_s * stride);
    const int Hs = H >> up1, Ws = W >> up1;
    const int plane1 = Hs * Ws;
    const int plane2 = H * W;
    // block-uniform bases -> force into SGPRs so tile setup stays scalar
    const unsigned boff1 = (unsigned)__builtin_amdgcn_readfirstlane(
        (int)(b_s * C1 * plane1));
    const unsigned boff2 = (unsigned)__builtin_amdgcn_readfirstlane(
        (int)(b_s * (Ctot - C1) * plane2));

    // ---- K-slice bounds + (tap, cb) init at slice start ----
    const int Tper = (Kp / BKT) / SK;
    const int t0 = kslice * Tper;
    const bool smallC = (Cp < 32);      // layer 1 only (Cp=8, never split)
    int tap, cb;
    if (smallC) { tap = kslot; cb = 0; }
    else {
        int prog = t0 * BKT;            // Cp % 32 == 0 for all split layers
        tap = prog / Cp;
        cb  = prog - tap * Cp + kslot * 8;
    }
    const int dtap = smallC ? (32 / Cp) : 0;

    // ---- wave/lane decomposition: wave tile = MW*16 rows x 64 cols ----
    const int wave = tid >> 6;
    const int wrow = wave * (MW * 16);
    const int lane = tid & 63;
    const int l16  = lane & 15;
    const int quad = lane >> 4;

    const short* pA[MW];
#pragma unroll
    for (int i = 0; i < MW; i++)
        pA[i] = Abf + (size_t)(m0 + wrow + i * 16 + l16) * Kp + quad * 8;

    floatx4 acc[MW][4];
#pragma unroll
    for (int i = 0; i < MW; i++)
#pragma unroll
        for (int j = 0; j < 4; j++)
            acc[i][j] = (floatx4){0.f, 0.f, 0.f, 0.f};

    if constexpr (LGW == 0) {
        // ======== direct-gather path (L1, L2), software-pipelined =========
        constexpr int CSX = (CS > 0) ? CS : 8;
        struct QS {
            float q00[CSX], q01[CSX], q10[CSX], q11[CSX];
            float w00, w01, w10, w11;
        };
        QS qa, qb;

        // issue the gathers for the CURRENT (tap, cb) state into q; advance.
        auto issueQ = [&](QS& q) {
            const int tapS = __builtin_amdgcn_readfirstlane(tap);
            const int cbS  = __builtin_amdgcn_readfirstlane(cb);
            const int tapc = min(tapS, K2 - 1);      // clamp for K-pad
            const float4 e = tab[tabBase + tapc];
            const float fr = e.x;
            const float col = wo_px + e.y;
            const int r0i = __float_as_int(e.z);
            const int r1i = __float_as_int(e.w);
            const float cf = floorf(col);
            const float fc = col - cf;
            const int c0 = ((int)cf) & (W - 1);
            const int c1 = (c0 + 1) & (W - 1);
            const float w11 = fr * fc;
            q.w11 = w11;
            q.w10 = fr - w11;             // fr*(1-fc)
            q.w01 = fc - w11;             // (1-fr)*fc
            q.w00 = 1.f - fr - fc + w11;  // (1-fr)*(1-fc)

            const char* sbase; unsigned o00, o01, o10, o11, planeB;
            if (cbS < C1) {              // SCALAR branch (cbS in SGPR)
                const int ra = (r0i >> up1) * Ws, rb = (r1i >> up1) * Ws;
                const int ca = c0 >> up1, cx = c1 >> up1;
                const unsigned base = boff1 + (unsigned)cbS * (unsigned)plane1;
                o00 = (base + ra + ca) * 4u; o01 = (base + ra + cx) * 4u;
                o10 = (base + rb + ca) * 4u; o11 = (base + rb + cx) * 4u;
                planeB = (unsigned)plane1 * 4u; sbase = (const char*)src1;
            } else {
                const int ra = r0i * W, rb = r1i * W;
                const unsigned base = boff2 + (unsigned)(cbS - C1) * (unsigned)plane2;
                o00 = (base + ra + c0) * 4u; o01 = (base + ra + c1) * 4u;
                o10 = (base + rb + c0) * 4u; o11 = (base + rb + c1) * 4u;
                planeB = (unsigned)plane2 * 4u; sbase = (const char*)src2;
            }
#pragma unroll
            for (int j = 0; j < CSX; j++) {
                q.q00[j] = *(const float*)(sbase + o00);
                q.q01[j] = *(const float*)(sbase + o01);
                q.q10[j] = *(const float*)(sbase + o10);
                q.q11[j] = *(const float*)(sbase + o11);
                o00 += planeB; o01 += planeB; o10 += planeB; o11 += planeB;
            }
            // advance (tap, cb)
            if (smallC) { tap += dtap; }
            else { cb += 32; if (cb >= Cp) { cb -= Cp; tap++; } }
        };

        auto interpStoreD = [&](const QS& q, int buf) {
            unsigned pk[4];
#pragma unroll
            for (int jj = 0; jj < 4; jj++) {
                if (2 * jj < CSX) {
                    float v0 = q.w00 * q.q00[2 * jj] + q.w01 * q.q01[2 * jj]
                             + q.w10 * q.q10[2 * jj] + q.w11 * q.q11[2 * jj];
                    float v1 = 0.f;
                    if (2 * jj + 1 < CSX)
                        v1 = q.w00 * q.q00[2 * jj + 1] + q.w01 * q.q01[2 * jj + 1]
                           + q.w10 * q.q10[2 * jj + 1] + q.w11 * q.q11[2 * jj + 1];
                    unsigned rr;
                    asm("v_cvt_pk_bf16_f32 %0, %1, %2"
                        : "=v"(rr) : "v"(v0), "v"(v1));
                    pk[jj] = rr;
                } else {
                    pk[jj] = 0u;         // zero-padded channels (finite!)
                }
            }
            *(uint4*)&Bs[buf][nn][kslot * 8] =
                make_uint4(pk[0], pk[1], pk[2], pk[3]);
        };

        auto mfmaStep = [&](int t) {
            const int k0 = t * BKT;
            const int buf = t & 1;
            short8 af[MW];
#pragma unroll
            for (int i = 0; i < MW; i++)
                af[i] = *(const short8*)(pA[i] + k0);
            short8 bfv[4];
#pragma unroll
            for (int j = 0; j < 4; j++)
                bfv[j] = *(const short8*)&Bs[buf][j * 16 + l16][quad * 8];
#pragma unroll
            for (int i = 0; i < MW; i++)
#pragma unroll
                for (int j = 0; j < 4; j++)
                    acc[i][j] = __builtin_amdgcn_mfma_f32_16x16x32_bf16(
                        af[i], bfv[j], acc[i][j], 0, 0, 0);
        };

        __syncthreads();   // table ready

        issueQ(qa);        // tile t0
        int t = t0;
        for (; t + 2 <= t0 + Tper; t += 2) {
            issueQ(qb);                 // tile t+1 in flight
            interpStoreD(qa, t & 1);    // consume tile t
            __syncthreads();
            mfmaStep(t);
            issueQ(qa);                 // tile t+2 in flight (harmless if OOB:
                                        // tapc clamps, cb wraps -> valid addrs)
            interpStoreD(qb, (t + 1) & 1);
            __syncthreads();
            mfmaStep(t + 1);
        }
        if (t < t0 + Tper) {            // odd Tper tail (13 for L1/L2)
            interpStoreD(qa, t & 1);
            __syncthreads();
            mfmaStep(t);
        }
    } else {
        // =================== COOP row-staged path (L3..L6) ================
        constexpr int WC    = 1 << LGW;
        constexpr int LGWS1 = LGW - UP;        // src1 row width (log2 floats)
        constexpr int NHO   = (LGWO >= 6) ? 1 : (64 >> LGWO);
        constexpr int NHO2  = NHO * 2;
        constexpr int LG2NHO = (NHO == 4) ? 3 : ((NHO == 2) ? 2 : 1);
        constexpr int NU    = 64 * NHO;        // units = 32ch x 2rows x NHO
        const int kslotU = __builtin_amdgcn_readfirstlane(kslot);

        // rows layout: unit u (= chL*2NHO + rowSel*NHO + hoL) occupies
        // Wsrc floats at dynLds + u*Wsrc*4; staged by global_load_lds_dwordx4
        // instrs each covering 1024B = 64 lanes x 16B (linear dest).
        auto stageTile = [&](int tapT, int cbT) {
            const bool s1 = (cbT < C1);
            const float* srcT = s1 ? src1 : src2;
            const int lgWt = s1 ? LGWS1 : LGW;
            const int upT  = s1 ? UP : 0;
            const int plT  = s1 ? plane1 : plane2;
            const unsigned chB = s1
                ? (boff1 + (unsigned)cbT * (unsigned)plane1)
                : (boff2 + (unsigned)(cbT - C1) * (unsigned)plane2);
            const int tapc2 = min(tapT, K2 - 1);
            const int lgLPU = lgWt - 2;                 // lanes per unit
            const int NIw = (NU << lgWt) >> 10;         // instrs per wave
            const int uW  = lane >> lgLPU;
            const unsigned colB = (unsigned)(lane & ((1 << lgLPU) - 1)) << 2;
            for (int ii = 0; ii < NIw; ii++) {
                const int idx = kslotU * NIw + ii;
                const int u = (idx << (6 - lgLPU)) + uW;
                const int chL = u >> LG2NHO;
                const int rem = u & (NHO2 - 1);
                const int hoL = rem & (NHO - 1);
                const float4 e = tab[hoL * K2 + tapc2];
                const float rsel = (rem >> (LG2NHO - 1)) ? e.w : e.z;
                const int r = __float_as_int(rsel) >> upT;
                const float* gp = srcT + (chB + (unsigned)chL * (unsigned)plT
                                          + ((unsigned)r << lgWt) + colB);
                __builtin_amdgcn_global_load_lds(
                    (const __attribute__((address_space(1))) void*)gp,
                    (__attribute__((address_space(3))) void*)(dynLds + (size_t)idx * 1024),
                    16, 0, 0);
            }
        };

        int tapS, cb0S;
        {
            int prog = t0 * BKT;
            tapS = prog / Cp;
            cb0S = prog - tapS * Cp;
        }

        __syncthreads();   // table ready

        stageTile(tapS, cb0S);
        short8 afc[MW];
#pragma unroll
        for (int i2 = 0; i2 < MW; i2++)
            afc[i2] = *(const short8*)(pA[i2] + t0 * BKT);

        for (int t = t0; t < t0 + Tper; t++) {
            tapS = __builtin_amdgcn_readfirstlane(tapS);
            cb0S = __builtin_amdgcn_readfirstlane(cb0S);
            const bool isS1 = (cb0S < C1);
            const int tapcI  = min(tapS, K2 - 1);

            asm volatile("s_waitcnt vmcnt(0)" ::: "memory");
            __syncthreads();             // bar1: rows(t) + afc landed

            // ---- interpolate from LDS rows -> Bs[0] ----
            // constexpr strides -> ds_read2_b32 {row0,row1} per corner pair
            auto interpStore = [&](auto lgwc, auto upc) {
                constexpr int LGWSRC = decltype(lgwc)::value;
                constexpr int UPX    = decltype(upc)::value;
                constexpr int STEPR  = NHO << LGWSRC;   // dwords, <=128
                constexpr int STEPC  = NHO2 << LGWSRC;
                const float4 e2 = tab[tabBase + tapcI];
                const float fr = e2.x;
                const float col = wo_px + e2.y;
                const float cf = floorf(col);
                const float fc = col - cf;
                const int c0 = ((int)cf) & (WC - 1);
                const int c1 = (c0 + 1) & (WC - 1);
                const int c0s = c0 >> UPX, c1s = c1 >> UPX;
                const float w11 = fr * fc;
                const float w10 = fr - w11;             // fr*(1-fc)
                const float w01 = fc - w11;             // (1-fr)*fc
                const float w00 = 1.f - fr - fc + w11;  // (1-fr)*(1-fc)
                const float* rowsF = (const float*)dynLds;
                const float* pc0 = rowsF
                    + ((((kslot * 8) << LG2NHO) + hoL_s) << LGWSRC) + c0s;
                const float* pc1 = pc0 + (c1s - c0s);
                float vv[8];
#pragma unroll
                for (int j = 0; j < 8; j++) {
                    const float x00 = pc0[0];
                    const float x10 = pc0[STEPR];
                    const float x01 = pc1[0];
                    const float x11 = pc1[STEPR];
                    vv[j] = w00 * x00 + w01 * x01 + w10 * x10 + w11 * x11;
                    pc0 += STEPC; pc1 += STEPC;
                }
                unsigned pk[4];
#pragma unroll
                for (int jj = 0; jj < 4; jj++) {
                    unsigned rr;
                    asm("v_cvt_pk_bf16_f32 %0, %1, %2"
                        : "=v"(rr) : "v"(vv[2 * jj]), "v"(vv[2 * jj + 1]));
                    pk[jj] = rr;
                }
                *(uint4*)&Bs[0][nn][kslot * 8] =
                    make_uint4(pk[0], pk[1], pk[2], pk[3]);
            };
            if (isS1) interpStore(IC<LGWS1>{}, IC<UP>{});
            else      interpStore(IC<LGW>{},   IC<0>{});

            __syncthreads();             // bar2: Bs ready; rows reusable

            // ---- issue next tile's A-frags + rows BEFORE the MFMA ----
            int tapN = tapS, cbN = cb0S + BKT;
            if (cbN >= Cp) { cbN = 0; tapN = tapS + 1; }
            const bool more = (t + 1 < t0 + Tper);
            short8 afn[MW];
            if (more) {
#pragma unroll
                for (int i2 = 0; i2 < MW; i2++)
                    afn[i2] = *(const short8*)(pA[i2] + (t + 1) * BKT);
                stageTile(tapN, cbN);
            }

            short8 bfr[4];
#pragma unroll
            for (int j = 0; j < 4; j++)
                bfr[j] = *(const short8*)&Bs[0][j * 16 + l16][quad * 8];
#pragma unroll
            for (int i2 = 0; i2 < MW; i2++)
#pragma unroll
                for (int j = 0; j < 4; j++)
                    acc[i2][j] = __builtin_amdgcn_mfma_f32_16x16x32_bf16(
                        afc[i2], bfr[j], acc[i2][j], 0, 0, 0);

            tapS = tapN; cb0S = cbN;
            if (more) {
#pragma unroll
                for (int i2 = 0; i2 < MW; i2++) afc[i2] = afn[i2];
            }
        }
    }

    // ---- epilogue (C/D layout col=lane&15, row=quad*4+reg) ----
    if (SK == 1) {
        // plain store + BN partials to UNIQUE per-(m,nblk) slots (no atomics)
#pragma unroll
        for (int i = 0; i < MW; i++) {
#pragma unroll
            for (int rr = 0; rr < 4; rr++) {
                const int m = m0 + wrow + i * 16 + quad * 4 + rr;
                const bool mv = (m < M);
                float s = 0.f, q = 0.f;
#pragma unroll
                for (int j = 0; j < 4; j++) {
                    const int n = n0 + j * 16 + l16;
                    const float v = acc[i][j][rr];
                    s += v; q += v * v;
                    if (mv) {
                        const int wo = n & (Wo - 1);
                        const int r  = n >> lWo;
                        const int ho = r & (Ho - 1);
                        const int b_ = r >> lHo;
                        Y[((size_t)b_ * M + m) * HW + (ho << lWo) + wo] = v;
                    }
                }
#pragma unroll
                for (int mask = 1; mask < 16; mask <<= 1) {
                    s += __shfl_xor(s, mask);
                    q += __shfl_xor(q, mask);
                }
                if (mv && l16 == 0)
                    part[(size_t)m * nBlkN + nblk] = make_float2(s, q);
            }
        }
    } else {
        // split-K: accumulate into zero-initialized Y (native f32 atomic add)
#pragma unroll
        for (int i = 0; i < MW; i++) {
#pragma unroll
            for (int j = 0; j < 4; j++) {
                const int n = n0 + j * 16 + l16;
                const int wo = n & (Wo - 1);
                const int r  = n >> lWo;
                const int ho = r & (Ho - 1);
                const int b_ = r >> lHo;
#pragma unroll
                for (int rr = 0; rr < 4; rr++) {
                    const int m = m0 + wrow + i * 16 + quad * 4 + rr;
                    if (m < M)
                        unsafeAtomicAdd(
                            &Y[((size_t)b_ * M + m) * HW + (ho << lWo) + wo],
                            acc[i][j][rr]);
                }
            }
        }
    }
}

// ---------------------------------------------------------------------------
// BN stats for split-K layers: grid (Co, 8), float partials -> part[c*8+sp].
// ---------------------------------------------------------------------------
__global__ __launch_bounds__(256) void bn_stats8_kernel(
    const float* __restrict__ Y, float2* __restrict__ part,
    int Co, int HW, int B)
{
    int co = blockIdx.x;
    int sp = blockIdx.y;
    int tid = threadIdx.x;
    int Nt = B * HW;
    int len = Nt >> 3;                  // Nt multiple of 8 (HW >= 512)
    int start = sp * len, end = start + len;
    float s = 0.f, q = 0.f;
    for (int idx = start + tid; idx < end; idx += 256) {
        int b = idx / HW; int o = idx - b * HW;
        float v = Y[((size_t)b * Co + co) * HW + o];
        s += v; q += v * v;
    }
    __shared__ float sh_s[256], sh_q[256];
    sh_s[tid] = s; sh_q[tid] = q;
    __syncthreads();
    for (int off = 128; off > 0; off >>= 1) {
        if (tid < off) { sh_s[tid] += sh_s[tid + off]; sh_q[tid] += sh_q[tid + off]; }
        __syncthreads();
    }
    if (tid == 0)
        part[co * 8 + sp] = make_float2(sh_s[0], sh_q[0]);
}

// ---------------------------------------------------------------------------
// BN finalize (L1 only, slots=nBlkN): reduce -> {sc, sf}.
// ---------------------------------------------------------------------------
__global__ __launch_bounds__(256) void bn_finalize_kernel(
    const float2* __restrict__ part, float2* __restrict__ scSf,
    const float* __restrict__ g, const float* __restrict__ bb,
    int nBlkN, int Nt)
{
    int c = blockIdx.x;
    int tid = threadIdx.x;
    double s = 0.0, q = 0.0;
    for (int k = tid; k < nBlkN; k += 256) {
        float2 p = part[(size_t)c * nBlkN + k];
        s += p.x; q += p.y;
    }
    __shared__ double sh_s[256], sh_q[256];
    sh_s[tid] = s; sh_q[tid] = q;
    __syncthreads();
    for (int off = 128; off > 0; off >>= 1) {
        if (tid < off) { sh_s[tid] += sh_s[tid + off]; sh_q[tid] += sh_q[tid + off]; }
        __syncthreads();
    }
    if (tid == 0) {
        double mean = sh_s[0] / Nt;
        double var = sh_q[0] / Nt - mean * mean;
        if (var < 0.0) var = 0.0;
        float sc = g[c] / sqrtf((float)var + 1e-5f);
        scSf[c] = make_float2(sc, bb[c] - (float)mean * sc);
    }
}

// Normalize + ReLU reading finalized {sc, sf} (L1 path).
__global__ __launch_bounds__(256) void bn_apply_kernel(
    float* __restrict__ Y, const float2* __restrict__ scSf,
    int Co, int HW, int total)
{
    int idx = blockIdx.x * 256 + threadIdx.x;
    if (idx >= total) return;
    int c = (idx / HW) % Co;
    float2 s = scSf[c];
    float v = Y[idx] * s.x + s.y;
    Y[idx] = v > 0.f ? v : 0.f;
}

// SK layers: finalize folded in — per-block reduce of the 8 partial slots
// (channel uniform per block since 256 | HW for all SK layers).
__global__ __launch_bounds__(256) void bn_apply_sk_kernel(
    float* __restrict__ Y, const float2* __restrict__ part,
    const float* __restrict__ g, const float* __restrict__ bb,
    int Co, int HW, int Nt, int total)
{
    int idx = blockIdx.x * 256 + threadIdx.x;
    int c = (idx / HW) % Co;
    __shared__ float s_sc, s_sf;
    if (threadIdx.x == 0) {
        double s = 0.0, q = 0.0;
        for (int p = 0; p < 8; p++) {
            float2 pp = part[c * 8 + p];
            s += pp.x; q += pp.y;
        }
        double mean = s / Nt;
        double var = q / Nt - mean * mean;
        if (var < 0.0) var = 0.0;
        float sc = g[c] / sqrtf((float)var + 1e-5f);
        s_sc = sc;
        s_sf = bb[c] - (float)mean * sc;
    }
    __syncthreads();
    if (idx >= total) return;
    float v = Y[idx] * s_sc + s_sf;
    Y[idx] = v > 0.f ? v : 0.f;
}

// ---------------------------------------------------------------------------
// Host orchestration. Workspace ~36 MB. Scratch Q reuse by lifetime:
// x1=Q (L1-2), x3=Q (L3-4), x4=Q (L5-6), x41=Q+512K (L6-7), x5=Q+1M (L7-8).
// Zeros for non-aliased SK outputs (x2, x31, d_out) hoisted+fused upfront;
// Q-aliased outputs (x3, x4, x41, x5) zeroed inline. All 8 wtrans batched
// into one launch at the start (weights are pure inputs).
// ---------------------------------------------------------------------------
extern "C" void kernel_launch(void* const* d_in, const int* in_sizes, int n_in,
                              void* d_out, int out_size, void* d_ws, size_t ws_size,
                              hipStream_t stream)
{
    const int B = 4;
    char* ws = (char*)d_ws;
    size_t off = 0;
    auto allocb = [&](size_t bytes) -> void* {
        void* p = ws + off;
        off = (off + bytes + 255) & ~(size_t)255;
        return p;
    };

    float2* part = (float2*)allocb((size_t)65536 * sizeof(float2));
    float2* scSf = (float2*)allocb(256 * sizeof(float2));
    float* x2  = (float*)allocb((size_t)B * 64  * 64 * 128 * 4);
    float* x31 = (float*)allocb((size_t)B * 128 * 32 * 64 * 4);
    float* Q   = (float*)allocb((size_t)B * 32  * 128 * 256 * 4);
    float* x1  = Q;
    float* x3  = Q;
    float* x4  = Q;
    float* x41 = Q + (size_t)B * 256 * 16 * 32;
    float* x5  = Q + 2 * (size_t)B * 256 * 16 * 32;

    //                      1     2     3    31     4    41     5     6
    static const int kH[8]  = {256, 128,  64,  32,  32,  16,  32,  64};
    static const int kW[8]  = {512, 256, 128,  64,  64,  32,  64, 128};
    static const int kK[8]  = {  7,   5,   5,   3,   3,   3,   3,   3};
    static const int kSt[8] = {  2,   2,   2,   1,   2,   1,   1,   1};
    static const int kC[8]  = {  6,  32,  64, 128, 128, 256, 384, 320};
    static const int kM[8]  = { 32,  64, 128, 128, 256, 256, 256, 128};
    // Grid tuning: L41 SK=8 (r26: was 256 blocks = 1 block/CU, grid-starved;
    // Kp=2304 % 256 == 0 so SK=8 costs no K-pad). L6 SK=2 (r16).
    static const int kMW[8] = {  1,   1,   1,   1,   1,   1,   2,   2};
    static const int kSK[8] = {  1,   2,   4,   4,   4,   8,   4,   2};

    int Cp_[8], Kp_[8], Mpad_[8];
    short* Abf[8];
    for (int i = 0; i < 8; i++) {
        int K2 = kK[i] * kK[i];
        int Cp = (kC[i] < 8) ? 8 : kC[i];
        int gran = 32 * kSK[i];
        int Kp = (K2 * Cp + gran - 1) / gran * gran;   // SK-slice aligned
        int Mpad = (kM[i] + 63) & ~63;
        Cp_[i] = Cp; Kp_[i] = Kp; Mpad_[i] = Mpad;
        Abf[i] = (short*)allocb((size_t)Mpad * Kp * sizeof(short));
    }
    (void)ws_size; (void)in_sizes; (void)n_in; (void)out_size;

    struct LCfg { const float *s1, *s2; int C1, up; float delta; int widx; float* Y; };
    const float* input = (const float*)d_in[0];
    LCfg L[8] = {
        { input, nullptr,   6, 0, PI_F / 32.f,  1, x1  },
        { x1,    nullptr,  32, 0, PI_F / 16.f,  5, x2  },
        { x2,    nullptr,  64, 0, PI_F / 4.f,   9, x3  },
        { x3,    nullptr, 128, 0, PI_F / 4.f,  13, x31 },
        { x31,   nullptr, 128, 0, PI_F / 2.f,  17, x4  },
        { x4,    nullptr, 256, 0, PI_F / 2.f,  21, x41 },
        { x41,   x31,     256, 1, PI_F / 4.f,  25, x5  },
        { x5,    x2,      256, 1, PI_F / 8.f,  29, (float*)d_out },
    };

    // ---- batched weight transpose (ONE launch for all 8 layers) ----
    {
        WtArgs wa;
        int cum = 0;
        for (int i = 0; i < 8; i++) {
            wa.A[i]   = (const float*)d_in[L[i].widx];
            wa.dst[i] = Abf[i];
            wa.M[i]   = kM[i];
            wa.K2[i]  = kK[i] * kK[i];
            wa.C[i]   = kC[i];
            wa.Cp[i]  = Cp_[i];
            wa.Kp[i]  = Kp_[i];
            wa.cum[i] = cum;
            cum += Mpad_[i] * Kp_[i];
        }
        wa.cum[8] = cum;
        wtrans_all_kernel<<<dim3((cum + 255) / 256), dim3(256), 0, stream>>>(wa);
    }

    // hoisted fused zero of non-aliased SK outputs
    {
        int n_x2 = B * 64 * 64 * 128;
        int n_x31 = B * 128 * 32 * 64;
        int n_out = B * 128 * 64 * 128;
        int tot = n_x2 + n_x31 + n_out;
        zero3_kernel<<<dim3((tot + 255) / 256), dim3(256), 0, stream>>>(
            x2, n_x2, x31, n_x31, (float*)d_out, n_out);
    }

    for (int i = 0; i < 8; i++) {
        const LCfg& c = L[i];
        int H = kH[i], W = kW[i], k = kK[i], st = kSt[i];
        int Ho = H / st, Wo = W / st;
        int K2 = k * k;
        int C  = kC[i], M = kM[i];
        int HW = Ho * Wo;
        int N  = B * HW;
        int lWo = __builtin_ctz(Wo), lHo = __builtin_ctz(Ho);
        const float* gam  = (const float*)d_in[c.widx + 2];
        const float* bet  = (const float*)d_in[c.widx + 3];
        int total = B * M * HW;

        int MWi = kMW[i], SKi = kSK[i];
        int nBlkM = Mpad_[i] / (64 * MWi);
        int nBlkN = N / BNT;
        int totalBlk = nBlkN * nBlkM * SKi;        // % 8 == 0 for all layers
        int lgM = __builtin_ctz(nBlkM);

        // COOP dynamic LDS: units (64*nHo) x widest-source row (floats)
        size_t dynB = 0;
        if (i >= 2) {
            int nHo_i = (Wo >= 64) ? 1 : (64 / Wo);
            int w1 = W >> c.up;
            int wmax = c.s2 ? W : w1;
            if (w1 > wmax) wmax = w1;
            dynB = (size_t)(64 * nHo_i) * (size_t)wmax * 4u;
        }

        // inline zero only for Q-aliased outputs (x3, x4, x41, x5)
        if (SKi > 1 && i >= 2 && i <= 6 && c.Y != x31)
            zero_kernel<<<dim3((total + 255) / 256), dim3(256), 0, stream>>>(
                c.Y, total);

        #define CONV_ARGS Abf[i], c.s1, c.s2, part, nBlkN, \
            c.C1, C, Cp_[i], H, W, c.up, K2, k, st, lWo, lHo, c.delta, \
            c.Y, M, Kp_[i], N, lgM
        #define LAUNCH(MW_, SK_, LGW_, UP_, LGWO_, CS_, DYN_) \
            sconv_mfma_kernel<MW_,SK_,LGW_,UP_,LGWO_,CS_> \
                <<<dim3(totalBlk), dim3(256), DYN_, stream>>>(CONV_ARGS)
        switch (i) {
            case 0: LAUNCH(1, 1, 0, 0, 0, 6, 0);    break;  // L1  direct CS=6
            case 1: LAUNCH(1, 2, 0, 0, 0, 0, 0);    break;  // L2  direct
            case 2: LAUNCH(1, 4, 7, 0, 6, 0, dynB); break;  // L3  W=128 Wo=64
            case 3: LAUNCH(1, 4, 6, 0, 6, 0, dynB); break;  // L31 W=64  Wo=64
            case 4: LAUNCH(1, 4, 6, 0, 5, 0, dynB); break;  // L4  W=64  Wo=32
            case 5: LAUNCH(1, 8, 5, 0, 5, 0, dynB); break;  // L41 W=32  Wo=32 SK8
            case 6: LAUNCH(2, 4, 6, 1, 6, 0, dynB); break;  // L5  W=64  Wo=64 up
            case 7: LAUNCH(2, 2, 7, 1, 7, 0, dynB); break;  // L6  W=128 Wo=128 up
        }
        #undef LAUNCH
        #undef CONV_ARGS

        if (SKi > 1) {
            bn_stats8_kernel<<<dim3(M, 8), dim3(256), 0, stream>>>(
                c.Y, part, M, HW, B);
            bn_apply_sk_kernel<<<dim3(total / 256), dim3(256), 0, stream>>>(
                c.Y, part, gam, bet, M, HW, N, total);
        } else {
            bn_finalize_kernel<<<dim3(M), dim3(256), 0, stream>>>(
                part, scSf, gam, bet, nBlkN, N);
            bn_apply_kernel<<<dim3(total / 256), dim3(256), 0, stream>>>(
                c.Y, scSf, M, HW, total);
        }
    }
}